// Round 1
// baseline (335.929 us; speedup 1.0000x reference)
//
#include <hip/hip_runtime.h>

#define EPS 1e-5f
constexpr int NB = 4096;   // batch
constexpr int ND = 128;    // D
constexpr int NO = 128;    // O
constexpr int BPB = 8;     // b-rows per block
constexpr int GEMM_GRID = NB / BPB;  // 512

// workspace layout (float offsets)
constexpr int WS_BN1SUM = 0;
constexpr int WS_BN1SQ  = 128;
constexpr int WS_S1     = 256;
constexpr int WS_T1     = 384;
constexpr int WS_W128   = 512;
constexpr int WS_CHSUM  = 640;
constexpr int WS_CHSQ   = 768;
constexpr int WS_S2     = 896;
constexpr int WS_C2     = 1024;
constexpr int WS_FLOATS = 1152;
// bf16 weights (128x128, k-major per row n) at byte offset WS_FLOATS*4

typedef short bf16x8 __attribute__((ext_vector_type(8)));
typedef float f32x4  __attribute__((ext_vector_type(4)));

__device__ inline unsigned short f2bf(float f) {
  unsigned int u = __float_as_uint(f);
  u += 0x7FFFu + ((u >> 16) & 1u);   // RNE; inputs are finite
  return (unsigned short)(u >> 16);
}

// ---------------- bn1 column stats: sum, sumsq over batch ----------------
__global__ __launch_bounds__(256) void k_bn1_stats(const float* __restrict__ x,
                                                   float* __restrict__ wsf) {
  __shared__ float ls[256], lq[256];
  int tid = threadIdx.x;
  int col = tid & 127, rh = tid >> 7;
  int rowBase = blockIdx.x * 32;
  float s = 0.f, q = 0.f;
  for (int r = rh; r < 32; r += 2) {
    float v = x[(rowBase + r) * ND + col];
    s += v; q += v * v;
  }
  ls[tid] = s; lq[tid] = q;
  __syncthreads();
  if (tid < 128) {
    atomicAdd(&wsf[WS_BN1SUM + tid], ls[tid] + ls[tid + 128]);
    atomicAdd(&wsf[WS_BN1SQ  + tid], lq[tid] + lq[tid + 128]);
  }
}

// ------------- finalize bn1 (s1,t1), convert W to bf16, extract w[:,128] -------------
__global__ __launch_bounds__(256) void k_prep(const float* __restrict__ fc_w,
                                              const float* __restrict__ g1,
                                              const float* __restrict__ b1,
                                              float* __restrict__ wsf,
                                              unsigned short* __restrict__ wbf) {
  int tid = threadIdx.x;
  int idx = blockIdx.x * 256 + tid;          // 0..16383
  int n = idx >> 7, k = idx & 127;
  wbf[idx] = f2bf(fc_w[n * 129 + k]);
  if (blockIdx.x == 0 && tid < 128) {
    float mu  = wsf[WS_BN1SUM + tid] * (1.f / NB);
    float var = wsf[WS_BN1SQ  + tid] * (1.f / NB) - mu * mu;
    float s1  = g1[tid] * rsqrtf(var + EPS);
    wsf[WS_S1 + tid]   = s1;
    wsf[WS_T1 + tid]   = b1[tid] - mu * s1;
    wsf[WS_W128 + tid] = fc_w[tid * 129 + 128];
  }
}

// ------------- finalize bn2 scale/shift (fc_b cancels analytically) -------------
__global__ __launch_bounds__(128) void k_fin2(const float* __restrict__ g2,
                                              const float* __restrict__ b2,
                                              float* __restrict__ wsf) {
  int o = threadIdx.x;
  const float invM = 1.f / (float)(NB * ND);
  float mean = wsf[WS_CHSUM + o] * invM;
  float var  = wsf[WS_CHSQ  + o] * invM - mean * mean;
  float s2 = g2[o] * rsqrtf(var + EPS);
  wsf[WS_S2 + o] = s2;
  wsf[WS_C2 + o] = b2[o] - mean * s2;
}

// ------------- fused feature-gen + GEMM; WRITE=false: stats, WRITE=true: normalize+store -------------
template <bool WRITE>
__global__ __launch_bounds__(256, 2) void k_gemm(const float* __restrict__ x,
                                                 const unsigned short* __restrict__ wbf,
                                                 float* __restrict__ wsf,
                                                 float* __restrict__ out) {
  __shared__ __align__(16) unsigned short Al[128 * 136];  // A tile, pitch 136 bf16
  __shared__ float zdup[256];                             // z duplicated for wrap-free reads
  __shared__ float ls1[128], lt1[128], lw[128], lsA[128], lsB[128];

  int tid  = threadIdx.x;
  int lane = tid & 63, wave = tid >> 6;
  int wr = wave >> 1, wc = wave & 1;       // wave computes rows [64*wr,+64) x cols [64*wc,+64)
  int lm = lane & 15, quad = lane >> 4;

  if (tid < 128) {
    ls1[tid] = wsf[WS_S1 + tid];
    lt1[tid] = wsf[WS_T1 + tid];
    lw[tid]  = wsf[WS_W128 + tid];
    if (WRITE) { lsA[tid] = wsf[WS_S2 + tid]; lsB[tid] = wsf[WS_C2 + tid]; }
  }

  // B fragments held in VGPRs for the whole kernel: B[k][n] = w[n][k] (bf16)
  // frag layout: n = lane&15 (+16*nt +64*wc), k = quad*8 + j (+32*kc)
  bf16x8 bfr[4][4];
  {
    const unsigned short* bp = wbf + (wc * 64 + lm) * 128 + quad * 8;
#pragma unroll
    for (int nt = 0; nt < 4; ++nt)
#pragma unroll
      for (int kc = 0; kc < 4; ++kc)
        bfr[nt][kc] = *(const bf16x8*)(bp + nt * 16 * 128 + kc * 32);
  }

  float colSum[4] = {0.f, 0.f, 0.f, 0.f};
  float colSq[4]  = {0.f, 0.f, 0.f, 0.f};

  __syncthreads();

  const int i_row = tid >> 1;           // A-gen: this thread's feature row
  const int kb    = (tid & 1) * 64;     // and k half

  for (int bi = 0; bi < BPB; ++bi) {
    int b = blockIdx.x * BPB + bi;
    // z = bn1(x[b,:])
    if (tid < 128) {
      float z = x[b * ND + tid] * ls1[tid] + lt1[tid];
      zdup[tid] = z; zdup[tid + 128] = z;
    }
    __syncthreads();
    // A[i][k] = relu(s * z[(i+k)&127]), s = (i+k<128) ? z[i-1] (1 if i==0) : z[i]
    {
      float sA = (i_row == 0) ? 1.0f : zdup[i_row - 1];
      float sB = zdup[i_row];
      unsigned short* dst = &Al[i_row * 136 + kb];
      int cbase = i_row + kb;
#pragma unroll
      for (int c8 = 0; c8 < 8; ++c8) {
        bf16x8 v;
#pragma unroll
        for (int j = 0; j < 8; ++j) {
          int c = cbase + c8 * 8 + j;               // <= 254
          float s = (c < 128) ? sA : sB;
          float p = fmaxf(s * zdup[c], 0.f);
          ((unsigned short*)&v)[j] = f2bf(p);
        }
        *(bf16x8*)(dst + c8 * 8) = v;
      }
    }
    __syncthreads();

    // MFMA: C(64x64 per wave) = A(rows) x B(cols), K=128 in 4 chunks of 32
    f32x4 acc[4][4];
#pragma unroll
    for (int mt = 0; mt < 4; ++mt)
#pragma unroll
      for (int nt = 0; nt < 4; ++nt) {
        f32x4 z4 = {0.f, 0.f, 0.f, 0.f};
        acc[mt][nt] = z4;
      }
#pragma unroll
    for (int kc = 0; kc < 4; ++kc) {
      bf16x8 af[4];
#pragma unroll
      for (int mt = 0; mt < 4; ++mt)
        af[mt] = *(const bf16x8*)&Al[(wr * 64 + mt * 16 + lm) * 136 + kc * 32 + quad * 8];
#pragma unroll
      for (int mt = 0; mt < 4; ++mt)
#pragma unroll
        for (int nt = 0; nt < 4; ++nt)
          acc[mt][nt] = __builtin_amdgcn_mfma_f32_16x16x32_bf16(af[mt], bfr[nt][kc],
                                                                acc[mt][nt], 0, 0, 0);
    }

    // epilogue: add fp32 rank-1 term (k=128 column: z_i^2 * w[o,128]), then stats or store
#pragma unroll
    for (int mt = 0; mt < 4; ++mt) {
      int r0 = wr * 64 + mt * 16 + quad * 4;
#pragma unroll
      for (int reg = 0; reg < 4; ++reg) {
        int r = r0 + reg;
        float zr = zdup[r];
        float zsq = zr * zr;
#pragma unroll
        for (int nt = 0; nt < 4; ++nt) {
          int col = wc * 64 + nt * 16 + lm;
          float v = acc[mt][nt][reg] + zsq * lw[col];
          if (WRITE) {
            out[((size_t)(b * ND + r)) * NO + col] = v * lsA[col] + lsB[col];
          } else {
            colSum[nt] += v;
            colSq[nt]  += v * v;
          }
        }
      }
    }
    __syncthreads();
  }

  if (!WRITE) {
    // reduce across quads (lanes sharing lm hold the same columns), one atomic per col
#pragma unroll
    for (int nt = 0; nt < 4; ++nt) {
      float s = colSum[nt], q = colSq[nt];
      s += __shfl_xor(s, 16); s += __shfl_xor(s, 32);
      q += __shfl_xor(q, 16); q += __shfl_xor(q, 32);
      if (quad == 0) {
        int col = wc * 64 + nt * 16 + lm;
        atomicAdd(&wsf[WS_CHSUM + col], s);
        atomicAdd(&wsf[WS_CHSQ  + col], q);
      }
    }
  }
}

extern "C" void kernel_launch(void* const* d_in, const int* in_sizes, int n_in,
                              void* d_out, int out_size, void* d_ws, size_t ws_size,
                              hipStream_t stream) {
  const float* x  = (const float*)d_in[0];
  const float* g1 = (const float*)d_in[1];
  const float* b1 = (const float*)d_in[2];
  const float* fw = (const float*)d_in[3];
  // d_in[4] = fc_b: cancels analytically in bn2 (shifts mean only)
  const float* g2 = (const float*)d_in[5];
  const float* b2 = (const float*)d_in[6];
  float* out = (float*)d_out;
  float* wsf = (float*)d_ws;
  unsigned short* wbf = (unsigned short*)((char*)d_ws + WS_FLOATS * 4);

  hipMemsetAsync(d_ws, 0, WS_FLOATS * 4, stream);                 // zero all stat accumulators
  k_bn1_stats<<<128, 256, 0, stream>>>(x, wsf);
  k_prep<<<64, 256, 0, stream>>>(fw, g1, b1, wsf, wbf);
  k_gemm<false><<<GEMM_GRID, 256, 0, stream>>>(x, wbf, wsf, nullptr);
  k_fin2<<<1, 128, 0, stream>>>(g2, b2, wsf);
  k_gemm<true><<<GEMM_GRID, 256, 0, stream>>>(x, wbf, wsf, out);
}